// Round 10
// baseline (128.106 us; speedup 1.0000x reference)
//
#include <hip/hip_runtime.h>

#define N_BINS 15
#define NREP 64     // one replica per (tid>>2): leader lanes sub=0 and sub=4
#define RSTRIDE 17  // odd stride: consecutive replicas -> distinct banks

typedef float f32x4 __attribute__((ext_vector_type(4)));

// One DPP butterfly step: max with a permuted copy (pure VALU, no LDS pipe).
template <int CTRL>
__device__ __forceinline__ unsigned dpp_umax(unsigned key) {
    unsigned other = (unsigned)__builtin_amdgcn_update_dpp(0, (int)key, CTRL, 0xF, 0xF, true);
    return key >= other ? key : other;
}

// 8-lane-group max: quad_perm[1,0,3,2], quad_perm[2,3,0,1], row_half_mirror.
__device__ __forceinline__ unsigned group8_umax(unsigned key) {
    key = dpp_umax<0xB1>(key);
    key = dpp_umax<0x4E>(key);
    key = dpp_umax<0x141>(key);
    return key;
}

// key = (fp32 bits & ~63) | (63 - col): positive floats compare as uints;
// ties on truncated value pick smallest col (jnp.argmax first-wins).
__device__ __forceinline__ unsigned pack_reduce(f32x4 v, unsigned colbase) {
    unsigned k0 = (__float_as_uint(v.x) & 0xFFFFFFC0u) | colbase;
    unsigned k1 = (__float_as_uint(v.y) & 0xFFFFFFC0u) | (colbase - 1u);
    unsigned k2 = (__float_as_uint(v.z) & 0xFFFFFFC0u) | (colbase - 2u);
    unsigned k3 = (__float_as_uint(v.w) & 0xFFFFFFC0u) | (colbase - 3u);
    unsigned a = k0 > k1 ? k0 : k1;
    unsigned b = k2 > k3 ? k2 : k3;
    return group8_umax(a > b ? a : b);
}

// ece = (1/n) * sum_b | sum_{rows in b} (conf - acc) |  (exact rewrite of the
// reference: safe==count when count>0; empty bins contribute 0). One RMW/row.
__device__ __forceinline__ void lane_update(unsigned key, int lab, float* rep) {
    const float best = __uint_as_float(key & 0xFFFFFFC0u);
    const int col = 63 - (int)(key & 63u);
    const float d = best - ((col == lab) ? 1.0f : 0.0f);
    if (best > 0.0f) {  // bin b covers (b/15,(b+1)/15]; conf==0 in no bin
        int b = (int)ceilf(best * 15.0f) - 1;
        b = b < 0 ? 0 : (b > N_BINS - 1 ? N_BINS - 1 : b);
        rep[b] += d;
    }
}

// ws layout: [0..14] per-bin sum of (conf-acc), ws[15] = completion ticket.
__global__ __launch_bounds__(256) void ece_kernel(const float* __restrict__ sm,
                                                  const int* __restrict__ labels,
                                                  float* __restrict__ ws,
                                                  float* __restrict__ out,
                                                  int n, int rows_per_wave, int nblocks) {
    __shared__ float s_hist[NREP * RSTRIDE];
    for (int i = threadIdx.x; i < NREP * RSTRIDE; i += blockDim.x) s_hist[i] = 0.f;
    __syncthreads();

    const int lane = threadIdx.x & 63;
    const int grp = lane >> 3;   // 0..7: row within each 8-row load
    const int sub = lane & 7;    // 0..7: float4 within the row
    const int wave_id = (blockIdx.x * blockDim.x + threadIdx.x) >> 6;

    float* rep = s_hist + (threadIdx.x >> 2) * RSTRIDE;  // private per leader lane
    const unsigned colbase = 63u - (unsigned)(sub * 4);

    const int n64 = n & ~63;
    const int row_begin = wave_id * rows_per_wave;
    int row_end = row_begin + rows_per_wave;
    if (row_end > n64) row_end = n64;

    // Start-phase stagger: begin at a pseudo-random tile of this wave's chunk
    // (wrap around), so the 8192 streams' first-touch addresses spread across
    // the L3/channel interleave instead of all hitting aligned residues at t=0.
    const int iters = (row_end - row_begin) >> 6;
    const int phase = (int)(((unsigned)wave_id * 2654435761u) >> 30);  // 0..3

    for (int t = 0; t < iters; ++t) {
        int idx = phase + t;
        if (idx >= iters) idx -= iters;                 // (phase+t) mod iters
        const int r0 = row_begin + (idx << 6);
        const f32x4* base = reinterpret_cast<const f32x4*>(sm + (size_t)r0 * 32);
        const f32x4 v0 = base[lane];          // rows r0    ..+7
        const f32x4 v1 = base[64 + lane];     // rows r0+8  ..+15
        const f32x4 v2 = base[128 + lane];    // rows r0+16 ..+23
        const f32x4 v3 = base[192 + lane];    // rows r0+24 ..+31
        const f32x4 v4 = base[256 + lane];    // rows r0+32 ..+39
        const f32x4 v5 = base[320 + lane];    // rows r0+40 ..+47
        const f32x4 v6 = base[384 + lane];    // rows r0+48 ..+55
        const f32x4 v7 = base[448 + lane];    // rows r0+56 ..+63
        const int lab0 = labels[r0 + grp];
        const int lab1 = labels[r0 + 8 + grp];
        const int lab2 = labels[r0 + 16 + grp];
        const int lab3 = labels[r0 + 24 + grp];
        const int lab4 = labels[r0 + 32 + grp];
        const int lab5 = labels[r0 + 40 + grp];
        const int lab6 = labels[r0 + 48 + grp];
        const int lab7 = labels[r0 + 56 + grp];
        const unsigned k0 = pack_reduce(v0, colbase);
        const unsigned k1 = pack_reduce(v1, colbase);
        const unsigned k2 = pack_reduce(v2, colbase);
        const unsigned k3 = pack_reduce(v3, colbase);
        const unsigned k4 = pack_reduce(v4, colbase);
        const unsigned k5 = pack_reduce(v5, colbase);
        const unsigned k6 = pack_reduce(v6, colbase);
        const unsigned k7 = pack_reduce(v7, colbase);
        // TWO leader lanes per group (sub 0 and 4) in ONE masked body.
        if ((sub & 3) == 0) {
            const bool hi = (sub != 0);
            lane_update(hi ? k4 : k0, hi ? lab4 : lab0, rep);
            lane_update(hi ? k5 : k1, hi ? lab5 : lab1, rep);
            lane_update(hi ? k6 : k2, hi ? lab6 : lab2, rep);
            lane_update(hi ? k7 : k3, hi ? lab7 : lab3, rep);
        }
    }

    __syncthreads();
    // fold 64 replicas -> one global atomic per bin per block
    if (threadIdx.x < N_BINS) {
        float s = 0.f;
        #pragma unroll
        for (int r = 0; r < NREP; ++r) s += s_hist[r * RSTRIDE + threadIdx.x];
        atomicAdd(&ws[threadIdx.x], s);
    }

    // tail rows [n64, n) (empty for n=2M): block 0, exact scalar path
    if (blockIdx.x == 0 && threadIdx.x < (n - n64)) {
        const int row = n64 + threadIdx.x;
        const float* rp = sm + (size_t)row * 32;
        float best = rp[0];
        int bi = 0;
        for (int c = 1; c < 32; ++c) {
            float x = rp[c];
            if (x > best) { best = x; bi = c; }
        }
        const float d = best - ((bi == labels[row]) ? 1.0f : 0.0f);
        if (best > 0.0f) {
            int b = (int)ceilf(best * 15.0f) - 1;
            b = b < 0 ? 0 : (b > N_BINS - 1 ? N_BINS - 1 : b);
            atomicAdd(&ws[b], d);
        }
    }

    // fused finalize (proven in R8): last block folds ws -> out. Each block
    // fences its adds before taking a ticket, so the last ticket-holder sees
    // all contributions (device-scope atomics; XCD-safe per G16).
    __syncthreads();
    if (threadIdx.x == 0) {
        __threadfence();
        unsigned old = atomicAdd(reinterpret_cast<unsigned*>(ws + N_BINS), 1u);
        if (old == (unsigned)(nblocks - 1)) {
            float ece = 0.f;
            #pragma unroll
            for (int b = 0; b < N_BINS; ++b) ece += fabsf(atomicAdd(&ws[b], 0.0f));
            out[0] = ece / (float)n;
        }
    }
}

extern "C" void kernel_launch(void* const* d_in, const int* in_sizes, int n_in,
                              void* d_out, int out_size, void* d_ws, size_t ws_size,
                              hipStream_t stream) {
    const float* sm = (const float*)d_in[0];
    const int* labels = (const int*)d_in[1];  // int64 in reference -> int32 in harness
    float* ws = (float*)d_ws;
    float* out = (float*)d_out;
    const int n = in_sizes[1];  // 2,000,000 rows

    // ws is poisoned (0xAA) once and never re-poisoned: zero bins+ticket EVERY call.
    (void)hipMemsetAsync(ws, 0, (N_BINS + 1) * sizeof(float), stream);

    const int block = 256;
    const int grid = 2048;                     // 8192 waves, 32 waves/CU
    const int waves = grid * (block / 64);
    const int n64 = n & ~63;
    const int chunks = (n64 / 64 + waves - 1) / waves;
    const int rows_per_wave = chunks * 64;     // n=2M -> 256 rows (32 KB) per wave

    ece_kernel<<<grid, block, 0, stream>>>(sm, labels, ws, out, n, rows_per_wave, grid);
}

// Round 11
// 62.029 us; speedup vs baseline: 2.0653x; 2.0653x over previous
//
#include <hip/hip_runtime.h>

#define N_BINS 15
#define NREP 64     // one replica per (tid>>2): leader lanes sub=0 and sub=4
#define RSTRIDE 17  // odd stride: consecutive replicas -> distinct banks

typedef float f32x4 __attribute__((ext_vector_type(4)));

// One DPP butterfly step: max with a permuted copy (pure VALU, no LDS pipe).
template <int CTRL>
__device__ __forceinline__ unsigned dpp_umax(unsigned key) {
    unsigned other = (unsigned)__builtin_amdgcn_update_dpp(0, (int)key, CTRL, 0xF, 0xF, true);
    return key >= other ? key : other;
}

// 8-lane-group max: quad_perm[1,0,3,2], quad_perm[2,3,0,1], row_half_mirror.
__device__ __forceinline__ unsigned group8_umax(unsigned key) {
    key = dpp_umax<0xB1>(key);
    key = dpp_umax<0x4E>(key);
    key = dpp_umax<0x141>(key);
    return key;
}

// key = (fp32 bits & ~63) | (63 - col): positive floats compare as uints;
// ties on truncated value pick smallest col (jnp.argmax first-wins).
__device__ __forceinline__ unsigned pack_reduce(f32x4 v, unsigned colbase) {
    unsigned k0 = (__float_as_uint(v.x) & 0xFFFFFFC0u) | colbase;
    unsigned k1 = (__float_as_uint(v.y) & 0xFFFFFFC0u) | (colbase - 1u);
    unsigned k2 = (__float_as_uint(v.z) & 0xFFFFFFC0u) | (colbase - 2u);
    unsigned k3 = (__float_as_uint(v.w) & 0xFFFFFFC0u) | (colbase - 3u);
    unsigned a = k0 > k1 ? k0 : k1;
    unsigned b = k2 > k3 ? k2 : k3;
    return group8_umax(a > b ? a : b);
}

// ece = (1/n) * sum_b | sum_{rows in b} (conf - acc) |  (exact rewrite of the
// reference: safe==count when count>0; empty bins contribute 0). One RMW/row.
__device__ __forceinline__ void lane_update(unsigned key, int lab, float* rep) {
    const float best = __uint_as_float(key & 0xFFFFFFC0u);
    const int col = 63 - (int)(key & 63u);
    const float d = best - ((col == lab) ? 1.0f : 0.0f);
    if (best > 0.0f) {  // bin b covers (b/15,(b+1)/15]; conf==0 in no bin
        int b = (int)ceilf(best * 15.0f) - 1;
        b = b < 0 ? 0 : (b > N_BINS - 1 ? N_BINS - 1 : b);
        rep[b] += d;
    }
}

// ws layout: [0..14] = per-bin sum of (conf - acc)
__global__ __launch_bounds__(256) void ece_bin_kernel(const float* __restrict__ sm,
                                                      const int* __restrict__ labels,
                                                      float* __restrict__ ws, int n,
                                                      int rows_per_wave) {
    __shared__ float s_hist[NREP * RSTRIDE];
    for (int i = threadIdx.x; i < NREP * RSTRIDE; i += blockDim.x) s_hist[i] = 0.f;
    __syncthreads();

    const int lane = threadIdx.x & 63;
    const int grp = lane >> 3;   // 0..7: row within each 8-row load
    const int sub = lane & 7;    // 0..7: float4 within the row
    const int wave_id = (blockIdx.x * blockDim.x + threadIdx.x) >> 6;

    float* rep = s_hist + (threadIdx.x >> 2) * RSTRIDE;  // private per leader lane
    const unsigned colbase = 63u - (unsigned)(sub * 4);

    // contiguous region per wave: sequential stream, 8 KB (64 rows) in flight/iter
    const int n64 = n & ~63;
    const int row_begin = wave_id * rows_per_wave;
    int row_end = row_begin + rows_per_wave;
    if (row_end > n64) row_end = n64;

    for (int r0 = row_begin; r0 < row_end; r0 += 64) {
        const f32x4* p = reinterpret_cast<const f32x4*>(sm + (size_t)r0 * 32) + lane;
        const f32x4* q = p + 256;  // +4096 B (global offset imm is 13-bit signed)
        f32x4 v0, v1, v2, v3, v4, v5, v6, v7;
        // sc0 = L1-bypass (gfx940+ glc): stream-once data never reuses L1, so
        // skip TCP allocation and let misses queue in the TCC path instead.
        asm volatile(
            "global_load_dwordx4 %0, %8, off sc0\n\t"
            "global_load_dwordx4 %1, %8, off offset:1024 sc0\n\t"
            "global_load_dwordx4 %2, %8, off offset:2048 sc0\n\t"
            "global_load_dwordx4 %3, %8, off offset:3072 sc0\n\t"
            "global_load_dwordx4 %4, %9, off sc0\n\t"
            "global_load_dwordx4 %5, %9, off offset:1024 sc0\n\t"
            "global_load_dwordx4 %6, %9, off offset:2048 sc0\n\t"
            "global_load_dwordx4 %7, %9, off offset:3072 sc0"
            : "=&v"(v0), "=&v"(v1), "=&v"(v2), "=&v"(v3),
              "=&v"(v4), "=&v"(v5), "=&v"(v6), "=&v"(v7)
            : "v"(p), "v"(q)
            : "memory");
        const int lab0 = labels[r0 + grp];    // plain loads; covered by the wait
        const int lab1 = labels[r0 + 8 + grp];
        const int lab2 = labels[r0 + 16 + grp];
        const int lab3 = labels[r0 + 24 + grp];
        const int lab4 = labels[r0 + 32 + grp];
        const int lab5 = labels[r0 + 40 + grp];
        const int lab6 = labels[r0 + 48 + grp];
        const int lab7 = labels[r0 + 56 + grp];
        asm volatile("s_waitcnt vmcnt(0)" ::: "memory");
        __builtin_amdgcn_sched_barrier(0);  // rule #18: pin consumers after wait
        const unsigned k0 = pack_reduce(v0, colbase);
        const unsigned k1 = pack_reduce(v1, colbase);
        const unsigned k2 = pack_reduce(v2, colbase);
        const unsigned k3 = pack_reduce(v3, colbase);
        const unsigned k4 = pack_reduce(v4, colbase);
        const unsigned k5 = pack_reduce(v5, colbase);
        const unsigned k6 = pack_reduce(v6, colbase);
        const unsigned k7 = pack_reduce(v7, colbase);
        // TWO leader lanes per group (sub 0 and 4) in ONE masked body:
        // chain stays 4 RMWs; both leader sets run in the same instructions.
        if ((sub & 3) == 0) {
            const bool hi = (sub != 0);
            lane_update(hi ? k4 : k0, hi ? lab4 : lab0, rep);
            lane_update(hi ? k5 : k1, hi ? lab5 : lab1, rep);
            lane_update(hi ? k6 : k2, hi ? lab6 : lab2, rep);
            lane_update(hi ? k7 : k3, hi ? lab7 : lab3, rep);
        }
    }

    __syncthreads();
    // fold 64 replicas -> one global atomic per bin per block
    if (threadIdx.x < N_BINS) {
        float s = 0.f;
        #pragma unroll
        for (int r = 0; r < NREP; ++r) s += s_hist[r * RSTRIDE + threadIdx.x];
        atomicAdd(&ws[threadIdx.x], s);
    }

    // tail rows [n64, n) (empty for n=2M): block 0, exact scalar path
    if (blockIdx.x == 0 && threadIdx.x < (n - n64)) {
        const int row = n64 + threadIdx.x;
        const float* rp = sm + (size_t)row * 32;
        float best = rp[0];
        int bi = 0;
        for (int c = 1; c < 32; ++c) {
            float x = rp[c];
            if (x > best) { best = x; bi = c; }
        }
        const float d = best - ((bi == labels[row]) ? 1.0f : 0.0f);
        if (best > 0.0f) {
            int b = (int)ceilf(best * 15.0f) - 1;
            b = b < 0 ? 0 : (b > N_BINS - 1 ? N_BINS - 1 : b);
            atomicAdd(&ws[b], d);
        }
    }
}

__global__ void ece_final_kernel(const float* __restrict__ ws, float* __restrict__ out, int n) {
    if (threadIdx.x == 0 && blockIdx.x == 0) {
        float ece = 0.f;
        #pragma unroll
        for (int b = 0; b < N_BINS; ++b) ece += fabsf(ws[b]);
        out[0] = ece / (float)n;
    }
}

extern "C" void kernel_launch(void* const* d_in, const int* in_sizes, int n_in,
                              void* d_out, int out_size, void* d_ws, size_t ws_size,
                              hipStream_t stream) {
    const float* sm = (const float*)d_in[0];
    const int* labels = (const int*)d_in[1];  // int64 in reference -> int32 in harness
    float* ws = (float*)d_ws;
    float* out = (float*)d_out;
    const int n = in_sizes[1];  // 2,000,000 rows

    // ws is poisoned (0xAA) once and never re-poisoned: zero it EVERY call.
    (void)hipMemsetAsync(ws, 0, N_BINS * sizeof(float), stream);

    const int block = 256;
    const int grid = 2048;                     // 8192 waves, 32 waves/CU
    const int waves = grid * (block / 64);
    const int n64 = n & ~63;
    const int chunks = (n64 / 64 + waves - 1) / waves;
    const int rows_per_wave = chunks * 64;     // n=2M -> 256 rows (32 KB) per wave

    ece_bin_kernel<<<grid, block, 0, stream>>>(sm, labels, ws, n, rows_per_wave);
    ece_final_kernel<<<1, 64, 0, stream>>>(ws, out, n);
}

// Round 12
// 50.446 us; speedup vs baseline: 2.5395x; 1.2296x over previous
//
#include <hip/hip_runtime.h>

#define N_BINS 15
#define NREP 64     // one replica per (tid>>2): leader lanes sub=0 and sub=4
#define RSTRIDE 17  // odd stride: consecutive replicas -> distinct banks
#define GRID 2048
#define SLOT 16     // floats per block partial-slot (15 bins + pad)

typedef float f32x4 __attribute__((ext_vector_type(4)));

// One DPP butterfly step: max with a permuted copy (pure VALU, no LDS pipe).
template <int CTRL>
__device__ __forceinline__ unsigned dpp_umax(unsigned key) {
    unsigned other = (unsigned)__builtin_amdgcn_update_dpp(0, (int)key, CTRL, 0xF, 0xF, true);
    return key >= other ? key : other;
}

// 8-lane-group max: quad_perm[1,0,3,2], quad_perm[2,3,0,1], row_half_mirror.
__device__ __forceinline__ unsigned group8_umax(unsigned key) {
    key = dpp_umax<0xB1>(key);
    key = dpp_umax<0x4E>(key);
    key = dpp_umax<0x141>(key);
    return key;
}

// key = (fp32 bits & ~63) | (63 - col): positive floats compare as uints;
// ties on truncated value pick smallest col (jnp.argmax first-wins).
__device__ __forceinline__ unsigned pack_reduce(f32x4 v, unsigned colbase) {
    unsigned k0 = (__float_as_uint(v.x) & 0xFFFFFFC0u) | colbase;
    unsigned k1 = (__float_as_uint(v.y) & 0xFFFFFFC0u) | (colbase - 1u);
    unsigned k2 = (__float_as_uint(v.z) & 0xFFFFFFC0u) | (colbase - 2u);
    unsigned k3 = (__float_as_uint(v.w) & 0xFFFFFFC0u) | (colbase - 3u);
    unsigned a = k0 > k1 ? k0 : k1;
    unsigned b = k2 > k3 ? k2 : k3;
    return group8_umax(a > b ? a : b);
}

// ece = (1/n) * sum_b | sum_{rows in b} (conf - acc) |  (exact rewrite of the
// reference: safe==count when count>0; empty bins contribute 0). One RMW/row.
__device__ __forceinline__ void lane_update(unsigned key, int lab, float* rep) {
    const float best = __uint_as_float(key & 0xFFFFFFC0u);
    const int col = 63 - (int)(key & 63u);
    const float d = best - ((col == lab) ? 1.0f : 0.0f);
    if (best > 0.0f) {  // bin b covers (b/15,(b+1)/15]; conf==0 in no bin
        int b = (int)ceilf(best * 15.0f) - 1;
        b = b < 0 ? 0 : (b > N_BINS - 1 ? N_BINS - 1 : b);
        rep[b] += d;
    }
}

// ws layout: GRID slots of SLOT floats; slot[bid][0..14] = block's per-bin
// partial sum of (conf-acc). Every slot written every call -> no memset.
__global__ __launch_bounds__(256) void ece_bin_kernel(const float* __restrict__ sm,
                                                      const int* __restrict__ labels,
                                                      float* __restrict__ ws, int n,
                                                      int rows_per_wave) {
    __shared__ float s_hist[NREP * RSTRIDE];
    for (int i = threadIdx.x; i < NREP * RSTRIDE; i += blockDim.x) s_hist[i] = 0.f;
    __syncthreads();

    const int lane = threadIdx.x & 63;
    const int grp = lane >> 3;   // 0..7: row within each 8-row load
    const int sub = lane & 7;    // 0..7: float4 within the row
    const int wave_id = (blockIdx.x * blockDim.x + threadIdx.x) >> 6;

    float* rep = s_hist + (threadIdx.x >> 2) * RSTRIDE;  // private per leader lane
    const unsigned colbase = 63u - (unsigned)(sub * 4);

    // contiguous region per wave: sequential stream, 8 KB (64 rows) in flight/iter
    const int n64 = n & ~63;
    const int row_begin = wave_id * rows_per_wave;
    int row_end = row_begin + rows_per_wave;
    if (row_end > n64) row_end = n64;

    for (int r0 = row_begin; r0 < row_end; r0 += 64) {
        const f32x4* p = reinterpret_cast<const f32x4*>(sm + (size_t)r0 * 32) + lane;
        const f32x4* q = p + 256;  // +4096 B (global offset imm is 13-bit signed)
        f32x4 v0, v1, v2, v3, v4, v5, v6, v7;
        asm volatile(
            "global_load_dwordx4 %0, %8, off sc0\n\t"
            "global_load_dwordx4 %1, %8, off offset:1024 sc0\n\t"
            "global_load_dwordx4 %2, %8, off offset:2048 sc0\n\t"
            "global_load_dwordx4 %3, %8, off offset:3072 sc0\n\t"
            "global_load_dwordx4 %4, %9, off sc0\n\t"
            "global_load_dwordx4 %5, %9, off offset:1024 sc0\n\t"
            "global_load_dwordx4 %6, %9, off offset:2048 sc0\n\t"
            "global_load_dwordx4 %7, %9, off offset:3072 sc0"
            : "=&v"(v0), "=&v"(v1), "=&v"(v2), "=&v"(v3),
              "=&v"(v4), "=&v"(v5), "=&v"(v6), "=&v"(v7)
            : "v"(p), "v"(q)
            : "memory");
        const int lab0 = labels[r0 + grp];    // plain loads; covered by the wait
        const int lab1 = labels[r0 + 8 + grp];
        const int lab2 = labels[r0 + 16 + grp];
        const int lab3 = labels[r0 + 24 + grp];
        const int lab4 = labels[r0 + 32 + grp];
        const int lab5 = labels[r0 + 40 + grp];
        const int lab6 = labels[r0 + 48 + grp];
        const int lab7 = labels[r0 + 56 + grp];
        asm volatile("s_waitcnt vmcnt(0)" ::: "memory");
        __builtin_amdgcn_sched_barrier(0);  // rule #18: pin consumers after wait
        const unsigned k0 = pack_reduce(v0, colbase);
        const unsigned k1 = pack_reduce(v1, colbase);
        const unsigned k2 = pack_reduce(v2, colbase);
        const unsigned k3 = pack_reduce(v3, colbase);
        const unsigned k4 = pack_reduce(v4, colbase);
        const unsigned k5 = pack_reduce(v5, colbase);
        const unsigned k6 = pack_reduce(v6, colbase);
        const unsigned k7 = pack_reduce(v7, colbase);
        // TWO leader lanes per group (sub 0 and 4) in ONE masked body.
        if ((sub & 3) == 0) {
            const bool hi = (sub != 0);
            lane_update(hi ? k4 : k0, hi ? lab4 : lab0, rep);
            lane_update(hi ? k5 : k1, hi ? lab5 : lab1, rep);
            lane_update(hi ? k6 : k2, hi ? lab6 : lab2, rep);
            lane_update(hi ? k7 : k3, hi ? lab7 : lab3, rep);
        }
    }

    // tail rows [n64, n) (empty for n=2M): block 0, LDS atomics BEFORE the fold
    if (blockIdx.x == 0 && threadIdx.x < (n - n64)) {
        const int row = n64 + threadIdx.x;
        const float* rp = sm + (size_t)row * 32;
        float best = rp[0];
        int bi = 0;
        for (int c = 1; c < 32; ++c) {
            float x = rp[c];
            if (x > best) { best = x; bi = c; }
        }
        const float d = best - ((bi == labels[row]) ? 1.0f : 0.0f);
        if (best > 0.0f) {
            int b = (int)ceilf(best * 15.0f) - 1;
            b = b < 0 ? 0 : (b > N_BINS - 1 ? N_BINS - 1 : b);
            atomicAdd(&s_hist[b], d);  // replica 0; folded below
        }
    }

    __syncthreads();
    // fold 64 replicas -> ONE plain store per bin to this block's private slot
    // (no global atomics: removes the 2048x15 same-address RMW tail; no memset
    //  needed since every slot is fully written every call)
    if (threadIdx.x < N_BINS) {
        float s = 0.f;
        #pragma unroll
        for (int r = 0; r < NREP; ++r) s += s_hist[r * RSTRIDE + threadIdx.x];
        ws[blockIdx.x * SLOT + threadIdx.x] = s;
    }
}

// Reduce GRID x SLOT partials -> ece. 256 threads: group g (=tid>>4, 16 groups)
// covers rows [g*128, g*128+128); lane-in-group b (=tid&15) owns bin b (b<15).
__global__ __launch_bounds__(256) void ece_final_kernel(const float* __restrict__ ws,
                                                        float* __restrict__ out, int n) {
    __shared__ float s_part[16][SLOT + 1];
    const int g = threadIdx.x >> 4;
    const int b = threadIdx.x & 15;
    float s = 0.f;
    if (b < N_BINS) {
        const int r0 = g * (GRID / 16);
        for (int i = 0; i < GRID / 16; ++i) s += ws[(r0 + i) * SLOT + b];
    }
    s_part[g][b] = s;
    __syncthreads();
    if (threadIdx.x == 0) {
        float ece = 0.f;
        #pragma unroll
        for (int bb = 0; bb < N_BINS; ++bb) {
            float t = 0.f;
            #pragma unroll
            for (int gg = 0; gg < 16; ++gg) t += s_part[gg][bb];
            ece += fabsf(t);
        }
        out[0] = ece / (float)n;
    }
}

extern "C" void kernel_launch(void* const* d_in, const int* in_sizes, int n_in,
                              void* d_out, int out_size, void* d_ws, size_t ws_size,
                              hipStream_t stream) {
    const float* sm = (const float*)d_in[0];
    const int* labels = (const int*)d_in[1];  // int64 in reference -> int32 in harness
    float* ws = (float*)d_ws;                 // needs GRID*SLOT*4 = 128 KB scratch
    float* out = (float*)d_out;
    const int n = in_sizes[1];  // 2,000,000 rows

    const int block = 256;
    const int waves = GRID * (block / 64);
    const int n64 = n & ~63;
    const int chunks = (n64 / 64 + waves - 1) / waves;
    const int rows_per_wave = chunks * 64;     // n=2M -> 256 rows (32 KB) per wave

    ece_bin_kernel<<<GRID, block, 0, stream>>>(sm, labels, ws, n, rows_per_wave);
    ece_final_kernel<<<1, 256, 0, stream>>>(ws, out, n);
}